// Round 21
// baseline (152.127 us; speedup 1.0000x reference)
//
#include <hip/hip_runtime.h>
#include <math.h>

#define BATCH 64
#define NN 512
#define MM 512
#define DD 128
#define BIGF 1e30f
#define KLOG2E 1.442695040888963f
#define LN2F   0.693147180559945f
#define BIGK   (BIGF * KLOG2E)

#define NA 768          // padded pair-antidiagonal count
#define NP 256          // pair-rows per batch

typedef __attribute__((ext_vector_type(2))) float f32x2;
typedef __attribute__((ext_vector_type(4))) float f32x4;
typedef __attribute__((ext_vector_type(8))) short s16x8;

// ---------------------------------------------------------------------------
// Kernel 1: FUSED cost GEMM (bf16 MFMA cross-term + exact fp32 row norms)
// -> diagonal-major f32 pairs (r15/r17 proven version).
//   Cd[b][a][ip] = f32x2{ C[2ip][a-ip], C[2ip+1][a-ip] } * (log2e/D)
// Block (0,0,0) zeroes the cross-kernel reduce counter.
// ---------------------------------------------------------------------------
__device__ __forceinline__ unsigned short f2bf(float f) {
    unsigned u = __float_as_uint(f);
    u += 0x7FFFu + ((u >> 16) & 1u);   // round-to-nearest-even
    return (unsigned short)(u >> 16);
}

#define LSI(A, IP) ((A) * 32 + ((IP) ^ ((A) & 31)))

__global__ __launch_bounds__(256) void cost_diag_mfma(const float* __restrict__ X,
                                                      const float* __restrict__ Y,
                                                      f32x2* __restrict__ Cd,
                                                      unsigned* __restrict__ cnt) {
    __shared__ alignas(16) short smem[2 * 64 * 128];   // 32 KB: Xbf | Ybf
    __shared__ float x2s[64];
    __shared__ float y2s[64];
    short* Xbf = smem;
    short* Ybf = smem + 64 * 128;
    f32x2* Ls  = (f32x2*)smem;                         // reused post-MFMA (24 KB)

    int b  = blockIdx.z;
    int ti = blockIdx.y * 64;
    int tj = blockIdx.x * 64;
    int t  = threadIdx.x;
    int l  = t & 63;
    int w  = t >> 6;

    if (b == 0 && ti == 0 && tj == 0 && t == 0) *cnt = 0u;  // reduce counter

    const float* Xb = X + ((size_t)b * NN + ti) * DD;
    const float* Yb = Y + ((size_t)b * MM + tj) * DD;

    int rw  = t >> 4;          // 0..15
    int k8l = t & 15;          // 16B slot (8 bf16)
    float xs_acc[4], ys_acc[4];
    #pragma unroll
    for (int it = 0; it < 4; ++it) {
        int r = rw + it * 16;
        const float* sx = Xb + (size_t)r * DD + k8l * 8;
        const float* sy = Yb + (size_t)r * DD + k8l * 8;
        float4 x0 = *(const float4*)sx;
        float4 x1 = *(const float4*)(sx + 4);
        float4 y0 = *(const float4*)sy;
        float4 y1 = *(const float4*)(sy + 4);
        xs_acc[it] = x0.x*x0.x + x0.y*x0.y + x0.z*x0.z + x0.w*x0.w
                   + x1.x*x1.x + x1.y*x1.y + x1.z*x1.z + x1.w*x1.w;
        ys_acc[it] = y0.x*y0.x + y0.y*y0.y + y0.z*y0.z + y0.w*y0.w
                   + y1.x*y1.x + y1.y*y1.y + y1.z*y1.z + y1.w*y1.w;
        s16x8 xv, yv;
        xv[0] = (short)f2bf(x0.x); xv[1] = (short)f2bf(x0.y);
        xv[2] = (short)f2bf(x0.z); xv[3] = (short)f2bf(x0.w);
        xv[4] = (short)f2bf(x1.x); xv[5] = (short)f2bf(x1.y);
        xv[6] = (short)f2bf(x1.z); xv[7] = (short)f2bf(x1.w);
        yv[0] = (short)f2bf(y0.x); yv[1] = (short)f2bf(y0.y);
        yv[2] = (short)f2bf(y0.z); yv[3] = (short)f2bf(y0.w);
        yv[4] = (short)f2bf(y1.x); yv[5] = (short)f2bf(y1.y);
        yv[6] = (short)f2bf(y1.z); yv[7] = (short)f2bf(y1.w);
        int sw = (r * 16 + (k8l ^ (r & 7))) * 8;
        *(s16x8*)&Xbf[sw] = xv;
        *(s16x8*)&Ybf[sw] = yv;
    }
    #pragma unroll
    for (int it = 0; it < 4; ++it) {
        float xs = xs_acc[it], ys = ys_acc[it];
        #pragma unroll
        for (int m = 8; m >= 1; m >>= 1) {
            xs += __shfl_xor(xs, m, 16);
            ys += __shfl_xor(ys, m, 16);
        }
        if (k8l == 0) { x2s[rw + it * 16] = xs; y2s[rw + it * 16] = ys; }
    }
    __syncthreads();

    f32x4 acc0 = {0.f,0.f,0.f,0.f}, acc1 = acc0, acc2 = acc0, acc3 = acc0;
    int ar = 16 * w + (l & 15);
    int kb = l >> 4;           // 0..3
    int c0 = l & 15;
    #pragma unroll
    for (int kk = 0; kk < 4; ++kk) {
        int k8 = kk * 4 + kb;
        s16x8 af = *(const s16x8*)&Xbf[(ar * 16 + (k8 ^ (ar & 7))) * 8];
        s16x8 b0 = *(const s16x8*)&Ybf[((c0     ) * 16 + (k8 ^ ((c0     ) & 7))) * 8];
        s16x8 b1 = *(const s16x8*)&Ybf[((c0 + 16) * 16 + (k8 ^ ((c0 + 16) & 7))) * 8];
        s16x8 b2 = *(const s16x8*)&Ybf[((c0 + 32) * 16 + (k8 ^ ((c0 + 32) & 7))) * 8];
        s16x8 b3 = *(const s16x8*)&Ybf[((c0 + 48) * 16 + (k8 ^ ((c0 + 48) & 7))) * 8];
        acc0 = __builtin_amdgcn_mfma_f32_16x16x32_bf16(af, b0, acc0, 0, 0, 0);
        acc1 = __builtin_amdgcn_mfma_f32_16x16x32_bf16(af, b1, acc1, 0, 0, 0);
        acc2 = __builtin_amdgcn_mfma_f32_16x16x32_bf16(af, b2, acc2, 0, 0, 0);
        acc3 = __builtin_amdgcn_mfma_f32_16x16x32_bf16(af, b3, acc3, 0, 0, 0);
    }

    const float inv = KLOG2E / (float)DD;
    int i0l = 16 * w + (l >> 4) * 4;
    float4 xx = *(const float4*)&x2s[i0l];
    float yy0 = y2s[c0];
    float yy1 = y2s[16 + c0];
    float yy2 = y2s[32 + c0];
    float yy3 = y2s[48 + c0];

    __syncthreads();           // all frag reads done; smem becomes Ls

    int ipl0 = i0l >> 1;
    #define WRT(ACC, YY, C) do {                                               \
        int jl = 16 * (C) + c0;                                                \
        float v0 = (xx.x + (YY) - 2.0f * (ACC)[0]) * inv;                      \
        float v1 = (xx.y + (YY) - 2.0f * (ACC)[1]) * inv;                      \
        float v2 = (xx.z + (YY) - 2.0f * (ACC)[2]) * inv;                      \
        float v3 = (xx.w + (YY) - 2.0f * (ACC)[3]) * inv;                      \
        Ls[LSI(ipl0 + jl, ipl0)]         = f32x2{v0, v1};                      \
        Ls[LSI(ipl0 + 1 + jl, ipl0 + 1)] = f32x2{v2, v3};                      \
    } while (0)
    WRT(acc0, yy0, 0); WRT(acc1, yy1, 1); WRT(acc2, yy2, 2); WRT(acc3, yy3, 3);
    #undef WRT
    __syncthreads();

    f32x2* Cdb = Cd + (size_t)b * (NA * NP);
    int base_a = (ti >> 1) + tj;
    int ipbase = (ti >> 1);
    #pragma unroll
    for (int k = 0; k < 12; ++k) {
        int f  = t + k * 256;
        int al = f >> 5;                   // 0..95
        int il = f & 31;
        int d  = al - il;                  // = local j
        if ((unsigned)d < 64u)
            Cdb[(size_t)(base_a + al) * NP + ipbase + il] = Ls[LSI(al, il)];
    }
}

// ---------------------------------------------------------------------------
// Kernel 2: soft-DTW — r17 structure VERBATIM (f32 Cd, dwordx2 loads, tied
// vmcnt(7), pipelined-q, DPP handoff, K=16 chunks) + fused deterministic
// final reduction (p==255: part[b], threadfence, ACQ_REL count; 64th block
// sums part[0..63] in fixed order -> out).
// ---------------------------------------------------------------------------
#define RING 8
#define KCH 16
#define ESK 15
#define NITER 51   // 816 steps >= 812 needed

__global__ __launch_bounds__(256) void sdtw_diag_kernel(const f32x2* __restrict__ Cd,
                                                        float* __restrict__ part,
                                                        float* __restrict__ out,
                                                        unsigned* __restrict__ cnt) {
    int b = blockIdx.x;
    int p = threadIdx.x;          // 0..255 (= pair-row ip)
    int l = p & 63;
    int w = p >> 6;
    int wm1 = (w == 0) ? 0 : (w - 1);
    int wsk = ESK * w;            // a = s - wsk
    int off = p + wsk;            // column: j = s - off
    const char* CbL = (const char*)Cd + (size_t)b * (NA * NP * 8) + p * 8;

    __shared__ alignas(16) f32x2 buf[2][4][KCH];   // 1 KB

    if (p < 128) ((f32x2*)buf)[p] = f32x2{BIGK, 1.0f};
    __syncthreads();

    float ps0 = BIGK, pq0 = 1.0f;      // row 2p   s at col j-1 / lagged q
    float ps1 = BIGK, pq1 = 1.0f;      // row 2p+1
    float nbc_s = BIGK, nbc_q = 1.0f;  // dpp up pair (s leads q by one col)
    float nbp_s = BIGK, nbp_q = 1.0f;
    f32x2 carry = {BIGK, 1.0f};        // prev-chunk slot15 (s,q)
    float qfl = 1.0f;                  // flush-shuffled neighbor q
    float eS = 0.f, lS = 0.f, dS = 0.f, fS = 0.f, gS = 0.f, hS = 0.f; // stash

    f32x2 b0, b1, b2, b3, b4, b5, b6, b7, b8, b9, b10, b11, b12, b13, b14, b15;
    b0=b1=b2=b3=b4=b5=b6=b7=b8=b9=b10=b11=b12=b13=b14=b15 = f32x2{BIGK, 1.0f};

    f32x2 r0, r1, r2, r3, r4, r5, r6, r7;

#define LOADPD(REG, AV) do {                                                   \
    int a_ = (AV);                                                             \
    a_ = a_ < 0 ? 0 : (a_ > NA - 1 ? NA - 1 : a_);                             \
    const char* pa_ = CbL + (unsigned)a_ * (NP * 8u);                          \
    asm volatile("global_load_dwordx2 %0, %1, off"                             \
                 : "=&v"(REG) : "v"(pa_) : "memory");                          \
} while (0)

    LOADPD(r0, 0 - wsk); LOADPD(r1, 1 - wsk); LOADPD(r2, 2 - wsk);
    LOADPD(r3, 3 - wsk); LOADPD(r4, 4 - wsk); LOADPD(r5, 5 - wsk);
    LOADPD(r6, 6 - wsk); LOADPD(r7, 7 - wsk);

#define SCHAIN(CC, S_, SUX, SDX) do {                                          \
    float su_, sd_;                                                            \
    if (l == 0) {                                                              \
        if (w == 0) { su_ = BIGK; sd_ = ((S_) == 0) ? 0.0f : BIGK; }           \
        else        { su_ = (SUX); sd_ = (SDX); }                              \
    } else { su_ = nbc_s; sd_ = nbp_s; }                                       \
    if ((unsigned)j_ < 512u) {                                                 \
        float lAs = ps0;                                                       \
        float m1;                                                              \
        asm("v_min3_f32 %0, %1, %2, %3" : "=v"(m1) : "v"(su_), "v"(lAs), "v"(sd_)); \
        asm("v_exp_f32 %0, %1" : "=v"(eS) : "v"(m1 - su_));                    \
        asm("v_exp_f32 %0, %1" : "=v"(lS) : "v"(m1 - lAs));                    \
        asm("v_exp_f32 %0, %1" : "=v"(dS) : "v"(m1 - sd_));                    \
        float sA = (CC).x + m1;                                                \
        float m2;                                                              \
        asm("v_min3_f32 %0, %1, %2, %3" : "=v"(m2) : "v"(sA), "v"(ps1), "v"(lAs)); \
        asm("v_exp_f32 %0, %1" : "=v"(fS) : "v"(m2 - sA));                     \
        asm("v_exp_f32 %0, %1" : "=v"(gS) : "v"(m2 - ps1));                    \
        asm("v_exp_f32 %0, %1" : "=v"(hS) : "v"(m2 - lAs));                    \
        ps0 = sA;                                                              \
        ps1 = (CC).y + m2;                                                     \
    }                                                                          \
} while (0)

#define QRESOLVE(JR, QUY, QDY) do {                                            \
    float qu_, qd_;                                                            \
    if (l == 0) {                                                              \
        if (w == 0) { qu_ = 1.0f; qd_ = 1.0f; }                                \
        else        { qu_ = (QUY); qd_ = (QDY); }                              \
    } else { qu_ = nbc_q; qd_ = nbp_q; }                                       \
    if ((unsigned)(JR) < 512u) {                                               \
        float qAo = pq0;                                                       \
        float qA = __builtin_fmaf(qu_, eS, __builtin_fmaf(pq0, lS, qd_ * dS)); \
        float qB = __builtin_fmaf(qA, fS, __builtin_fmaf(pq1, gS, qAo * hS));  \
        pq0 = qA; pq1 = qB;                                                    \
    }                                                                          \
} while (0)

#define STEPN(REG, SIG, BSS, BSQ, SUX, SDX, QUY, QDY) do {                     \
    int s_ = sbase + (SIG);                                                    \
    int j_ = s_ - off;                                                         \
    f32x2 cc;                                                                  \
    asm volatile("s_waitcnt vmcnt(7)" : "=v"(cc) : "0"(REG));                  \
    QRESOLVE(j_ - 1, QUY, QDY);                                                \
    BSQ.y = pq1;                                                               \
    SCHAIN(cc, s_, SUX, SDX);                                                  \
    BSS.x = ps1;                                                               \
    float shs_, shq_;                                                          \
    asm("v_mov_b32_dpp %0, %2 wave_shr:1 row_mask:0xf bank_mask:0xf\n\t"       \
        "v_mov_b32_dpp %1, %3 wave_shr:1 row_mask:0xf bank_mask:0xf"           \
        : "=v"(shs_), "=v"(shq_) : "v"(ps1), "v"(pq1));                        \
    nbp_s = nbc_s; nbc_s = shs_;                                               \
    nbp_q = nbc_q; nbc_q = shq_;                                               \
    LOADPD(REG, s_ + RING - wsk);                                              \
} while (0)

#define STEP0(REG, BSS) do {                                                   \
    int s_ = sbase;                                                            \
    int j_ = s_ - off;                                                         \
    f32x2 cc;                                                                  \
    asm volatile("s_waitcnt vmcnt(7)" : "=v"(cc) : "0"(REG));                  \
    SCHAIN(cc, s_, c0[0], carry.x);                                            \
    BSS.x = ps1;                                                               \
    float shs_;                                                                \
    asm("v_mov_b32_dpp %0, %1 wave_shr:1 row_mask:0xf bank_mask:0xf"           \
        : "=v"(shs_) : "v"(ps1));                                              \
    nbp_s = nbc_s; nbc_s = shs_;                                               \
    nbp_q = nbc_q; nbc_q = qfl;                                                \
    LOADPD(REG, s_ + RING - wsk);                                              \
} while (0)

#define FLUSHQ() do {                                                          \
    int jr_ = sbase + 15 - off;                                                \
    QRESOLVE(jr_, c7[3], c7[1]);                                               \
    b15.y = pq1;                                                               \
    asm("v_mov_b32_dpp %0, %1 wave_shr:1 row_mask:0xf bank_mask:0xf"           \
        : "=v"(qfl) : "v"(pq1));                                               \
} while (0)

#define RENORMD(S, Q) do {                                                     \
    int e_ = (__float_as_int(Q) >> 23) - 127;                                  \
    Q = __int_as_float(__float_as_int(Q) - (e_ << 23));                        \
    S = S - (float)e_;                                                         \
} while (0)

    for (int I = 0; I < NITER; ++I) {
        asm volatile("s_waitcnt lgkmcnt(0)" ::: "memory");
        __builtin_amdgcn_s_barrier();
        asm volatile("" ::: "memory");
        const f32x4* rq = (const f32x4*)&buf[(I + 1) & 1][wm1][0];
        f32x4 c0 = rq[0], c1 = rq[1], c2 = rq[2], c3 = rq[3];
        f32x4 c4 = rq[4], c5 = rq[5], c6 = rq[6], c7 = rq[7];
        int sbase = I * KCH;
        STEP0(r0, b0);
        STEPN(r1, 1,  b1,  b0,  c0[2], c0[0], c0[1], carry.y);
        STEPN(r2, 2,  b2,  b1,  c1[0], c0[2], c0[3], c0[1]);
        STEPN(r3, 3,  b3,  b2,  c1[2], c1[0], c1[1], c0[3]);
        STEPN(r4, 4,  b4,  b3,  c2[0], c1[2], c1[3], c1[1]);
        STEPN(r5, 5,  b5,  b4,  c2[2], c2[0], c2[1], c1[3]);
        STEPN(r6, 6,  b6,  b5,  c3[0], c2[2], c2[3], c2[1]);
        STEPN(r7, 7,  b7,  b6,  c3[2], c3[0], c3[1], c2[3]);
        STEPN(r0, 8,  b8,  b7,  c4[0], c3[2], c3[3], c3[1]);
        STEPN(r1, 9,  b9,  b8,  c4[2], c4[0], c4[1], c3[3]);
        STEPN(r2, 10, b10, b9,  c5[0], c4[2], c4[3], c4[1]);
        STEPN(r3, 11, b11, b10, c5[2], c5[0], c5[1], c4[3]);
        STEPN(r4, 12, b12, b11, c6[0], c5[2], c5[3], c5[1]);
        STEPN(r5, 13, b13, b12, c6[2], c6[0], c6[1], c5[3]);
        STEPN(r6, 14, b14, b13, c7[0], c6[2], c6[3], c6[1]);
        STEPN(r7, 15, b15, b14, c7[2], c7[0], c7[1], c6[3]);
        FLUSHQ();
        carry = f32x2{c7[2], c7[3]};
        if (l == 63) {
            f32x2* wbp = &buf[I & 1][w][0];
            wbp[0]  = b0;  wbp[1]  = b1;  wbp[2]  = b2;  wbp[3]  = b3;
            wbp[4]  = b4;  wbp[5]  = b5;  wbp[6]  = b6;  wbp[7]  = b7;
            wbp[8]  = b8;  wbp[9]  = b9;  wbp[10] = b10; wbp[11] = b11;
            wbp[12] = b12; wbp[13] = b13; wbp[14] = b14; wbp[15] = b15;
        }
        RENORMD(ps0, pq0);
        RENORMD(ps1, pq1);
    }

    if (p == 255) {   // cell (511,511) resolved in-loop; fused reduction
        float lg;
        asm("v_log_f32 %0, %1" : "=v"(lg) : "v"(pq1));
        part[b] = (ps1 - lg) * LN2F;
        __threadfence();
        unsigned prev = __hip_atomic_fetch_add(cnt, 1u, __ATOMIC_ACQ_REL,
                                               __HIP_MEMORY_SCOPE_AGENT);
        if (prev == BATCH - 1u) {          // last block: deterministic sum
            const volatile float* vp = part;
            float s = 0.0f;
            #pragma unroll
            for (int i = 0; i < BATCH; ++i) s += vp[i];
            out[0] = s / (float)(BATCH * NN);
        }
    }
#undef STEPN
#undef STEP0
#undef FLUSHQ
#undef QRESOLVE
#undef SCHAIN
#undef LOADPD
#undef RENORMD
}

// ---------------------------------------------------------------------------
extern "C" void kernel_launch(void* const* d_in, const int* in_sizes, int n_in,
                              void* d_out, int out_size, void* d_ws, size_t ws_size,
                              hipStream_t stream) {
    const float* X = (const float*)d_in[0];
    const float* Y = (const float*)d_in[1];
    float* out = (float*)d_out;
    char* ws = (char*)d_ws;

    const size_t cdBytes = (size_t)BATCH * NA * NP * 8;       // 96 MiB (f32x2)

    f32x2*    Cd   = (f32x2*)ws;
    float*    part = (float*)(ws + cdBytes);
    unsigned* cnt  = (unsigned*)(ws + cdBytes + 256);

    dim3 g(MM / 64, NN / 64, BATCH);
    cost_diag_mfma<<<g, 256, 0, stream>>>(X, Y, Cd, cnt);

    sdtw_diag_kernel<<<BATCH, 256, 0, stream>>>(Cd, part, out, cnt);
}

// Round 22
// 145.364 us; speedup vs baseline: 1.0465x; 1.0465x over previous
//
#include <hip/hip_runtime.h>
#include <math.h>

#define BATCH 64
#define NN 512
#define MM 512
#define DD 128
#define BIGF 1e30f
#define KLOG2E 1.442695040888963f
#define LN2F   0.693147180559945f
#define BIGK   (BIGF * KLOG2E)

#define NA 768          // padded pair-antidiagonal count
#define NP 256          // pair-rows per batch

typedef __attribute__((ext_vector_type(2))) float f32x2;
typedef __attribute__((ext_vector_type(4))) float f32x4;
typedef __attribute__((ext_vector_type(8))) short s16x8;

// ---------------------------------------------------------------------------
// Kernel 1: FUSED cost GEMM (bf16 MFMA cross-term + exact fp32 row norms
// computed in-tile) -> diagonal-major f32 pairs. (r17 proven version)
//   Cd[b][a][ip] = f32x2{ C[2ip][a-ip], C[2ip+1][a-ip] } * (log2e/D)
// ---------------------------------------------------------------------------
__device__ __forceinline__ unsigned short f2bf(float f) {
    unsigned u = __float_as_uint(f);
    u += 0x7FFFu + ((u >> 16) & 1u);   // round-to-nearest-even
    return (unsigned short)(u >> 16);
}

#define LSI(A, IP) ((A) * 32 + ((IP) ^ ((A) & 31)))

__global__ __launch_bounds__(256) void cost_diag_mfma(const float* __restrict__ X,
                                                      const float* __restrict__ Y,
                                                      f32x2* __restrict__ Cd) {
    __shared__ alignas(16) short smem[2 * 64 * 128];   // 32 KB: Xbf | Ybf
    __shared__ float x2s[64];
    __shared__ float y2s[64];
    short* Xbf = smem;
    short* Ybf = smem + 64 * 128;
    f32x2* Ls  = (f32x2*)smem;                         // reused post-MFMA (24 KB)

    int b  = blockIdx.z;
    int ti = blockIdx.y * 64;
    int tj = blockIdx.x * 64;
    int t  = threadIdx.x;
    int l  = t & 63;
    int w  = t >> 6;

    const float* Xb = X + ((size_t)b * NN + ti) * DD;
    const float* Yb = Y + ((size_t)b * MM + tj) * DD;

    int rw  = t >> 4;          // 0..15
    int k8l = t & 15;          // 16B slot (8 bf16)
    float xs_acc[4], ys_acc[4];
    #pragma unroll
    for (int it = 0; it < 4; ++it) {
        int r = rw + it * 16;
        const float* sx = Xb + (size_t)r * DD + k8l * 8;
        const float* sy = Yb + (size_t)r * DD + k8l * 8;
        float4 x0 = *(const float4*)sx;
        float4 x1 = *(const float4*)(sx + 4);
        float4 y0 = *(const float4*)sy;
        float4 y1 = *(const float4*)(sy + 4);
        xs_acc[it] = x0.x*x0.x + x0.y*x0.y + x0.z*x0.z + x0.w*x0.w
                   + x1.x*x1.x + x1.y*x1.y + x1.z*x1.z + x1.w*x1.w;
        ys_acc[it] = y0.x*y0.x + y0.y*y0.y + y0.z*y0.z + y0.w*y0.w
                   + y1.x*y1.x + y1.y*y1.y + y1.z*y1.z + y1.w*y1.w;
        s16x8 xv, yv;
        xv[0] = (short)f2bf(x0.x); xv[1] = (short)f2bf(x0.y);
        xv[2] = (short)f2bf(x0.z); xv[3] = (short)f2bf(x0.w);
        xv[4] = (short)f2bf(x1.x); xv[5] = (short)f2bf(x1.y);
        xv[6] = (short)f2bf(x1.z); xv[7] = (short)f2bf(x1.w);
        yv[0] = (short)f2bf(y0.x); yv[1] = (short)f2bf(y0.y);
        yv[2] = (short)f2bf(y0.z); yv[3] = (short)f2bf(y0.w);
        yv[4] = (short)f2bf(y1.x); yv[5] = (short)f2bf(y1.y);
        yv[6] = (short)f2bf(y1.z); yv[7] = (short)f2bf(y1.w);
        int sw = (r * 16 + (k8l ^ (r & 7))) * 8;
        *(s16x8*)&Xbf[sw] = xv;
        *(s16x8*)&Ybf[sw] = yv;
    }
    #pragma unroll
    for (int it = 0; it < 4; ++it) {
        float xs = xs_acc[it], ys = ys_acc[it];
        #pragma unroll
        for (int m = 8; m >= 1; m >>= 1) {
            xs += __shfl_xor(xs, m, 16);
            ys += __shfl_xor(ys, m, 16);
        }
        if (k8l == 0) { x2s[rw + it * 16] = xs; y2s[rw + it * 16] = ys; }
    }
    __syncthreads();

    f32x4 acc0 = {0.f,0.f,0.f,0.f}, acc1 = acc0, acc2 = acc0, acc3 = acc0;
    int ar = 16 * w + (l & 15);
    int kb = l >> 4;           // 0..3
    int c0 = l & 15;
    #pragma unroll
    for (int kk = 0; kk < 4; ++kk) {
        int k8 = kk * 4 + kb;
        s16x8 af = *(const s16x8*)&Xbf[(ar * 16 + (k8 ^ (ar & 7))) * 8];
        s16x8 b0 = *(const s16x8*)&Ybf[((c0     ) * 16 + (k8 ^ ((c0     ) & 7))) * 8];
        s16x8 b1 = *(const s16x8*)&Ybf[((c0 + 16) * 16 + (k8 ^ ((c0 + 16) & 7))) * 8];
        s16x8 b2 = *(const s16x8*)&Ybf[((c0 + 32) * 16 + (k8 ^ ((c0 + 32) & 7))) * 8];
        s16x8 b3 = *(const s16x8*)&Ybf[((c0 + 48) * 16 + (k8 ^ ((c0 + 48) & 7))) * 8];
        acc0 = __builtin_amdgcn_mfma_f32_16x16x32_bf16(af, b0, acc0, 0, 0, 0);
        acc1 = __builtin_amdgcn_mfma_f32_16x16x32_bf16(af, b1, acc1, 0, 0, 0);
        acc2 = __builtin_amdgcn_mfma_f32_16x16x32_bf16(af, b2, acc2, 0, 0, 0);
        acc3 = __builtin_amdgcn_mfma_f32_16x16x32_bf16(af, b3, acc3, 0, 0, 0);
    }

    const float inv = KLOG2E / (float)DD;
    int i0l = 16 * w + (l >> 4) * 4;
    float4 xx = *(const float4*)&x2s[i0l];
    float yy0 = y2s[c0];
    float yy1 = y2s[16 + c0];
    float yy2 = y2s[32 + c0];
    float yy3 = y2s[48 + c0];

    __syncthreads();           // all frag reads done; smem becomes Ls

    int ipl0 = i0l >> 1;
    #define WRT(ACC, YY, C) do {                                               \
        int jl = 16 * (C) + c0;                                                \
        float v0 = (xx.x + (YY) - 2.0f * (ACC)[0]) * inv;                      \
        float v1 = (xx.y + (YY) - 2.0f * (ACC)[1]) * inv;                      \
        float v2 = (xx.z + (YY) - 2.0f * (ACC)[2]) * inv;                      \
        float v3 = (xx.w + (YY) - 2.0f * (ACC)[3]) * inv;                      \
        Ls[LSI(ipl0 + jl, ipl0)]         = f32x2{v0, v1};                      \
        Ls[LSI(ipl0 + 1 + jl, ipl0 + 1)] = f32x2{v2, v3};                      \
    } while (0)
    WRT(acc0, yy0, 0); WRT(acc1, yy1, 1); WRT(acc2, yy2, 2); WRT(acc3, yy3, 3);
    #undef WRT
    __syncthreads();

    f32x2* Cdb = Cd + (size_t)b * (NA * NP);
    int base_a = (ti >> 1) + tj;
    int ipbase = (ti >> 1);
    #pragma unroll
    for (int k = 0; k < 12; ++k) {
        int f  = t + k * 256;
        int al = f >> 5;                   // 0..95
        int il = f & 31;
        int d  = al - il;                  // = local j
        if ((unsigned)d < 64u)
            Cdb[(size_t)(base_a + al) * NP + ipbase + il] = Ls[LSI(al, il)];
    }
}

// ---------------------------------------------------------------------------
// Kernel 2: soft-DTW — r17 measured-best version VERBATIM. 4 waves x 2
// rows/lane; (s,q) log-free carry with the q/exp path software-pipelined one
// step (exps stashed at step s-1, consumed at step s -> zero trans-latency on
// the chain); DPP lane handoff; K=16 chunk LDS boundary exchange; depth-8 asm
// global ring with tied-register vmcnt(7).
// ---------------------------------------------------------------------------
#define RING 8
#define KCH 16
#define ESK 15
#define NITER 51   // 816 steps >= 812 needed

__global__ __launch_bounds__(256) void sdtw_diag_kernel(const f32x2* __restrict__ Cd,
                                                        float* __restrict__ part) {
    int b = blockIdx.x;
    int p = threadIdx.x;          // 0..255 (= pair-row ip)
    int l = p & 63;
    int w = p >> 6;
    int wm1 = (w == 0) ? 0 : (w - 1);
    int wsk = ESK * w;            // a = s - wsk
    int off = p + wsk;            // column: j = s - off
    const char* CbL = (const char*)Cd + (size_t)b * (NA * NP * 8) + p * 8;

    __shared__ alignas(16) f32x2 buf[2][4][KCH];   // 1 KB

    if (p < 128) ((f32x2*)buf)[p] = f32x2{BIGK, 1.0f};
    __syncthreads();

    float ps0 = BIGK, pq0 = 1.0f;      // row 2p   s at col j-1 / lagged q
    float ps1 = BIGK, pq1 = 1.0f;      // row 2p+1
    float nbc_s = BIGK, nbc_q = 1.0f;  // dpp up pair (s leads q by one col)
    float nbp_s = BIGK, nbp_q = 1.0f;
    f32x2 carry = {BIGK, 1.0f};        // prev-chunk slot15 (s,q)
    float qfl = 1.0f;                  // flush-shuffled neighbor q
    float eS = 0.f, lS = 0.f, dS = 0.f, fS = 0.f, gS = 0.f, hS = 0.f; // stash

    f32x2 b0, b1, b2, b3, b4, b5, b6, b7, b8, b9, b10, b11, b12, b13, b14, b15;
    b0=b1=b2=b3=b4=b5=b6=b7=b8=b9=b10=b11=b12=b13=b14=b15 = f32x2{BIGK, 1.0f};

    f32x2 r0, r1, r2, r3, r4, r5, r6, r7;

#define LOADPD(REG, AV) do {                                                   \
    int a_ = (AV);                                                             \
    a_ = a_ < 0 ? 0 : (a_ > NA - 1 ? NA - 1 : a_);                             \
    const char* pa_ = CbL + (unsigned)a_ * (NP * 8u);                          \
    asm volatile("global_load_dwordx2 %0, %1, off"                             \
                 : "=&v"(REG) : "v"(pa_) : "memory");                          \
} while (0)

    LOADPD(r0, 0 - wsk); LOADPD(r1, 1 - wsk); LOADPD(r2, 2 - wsk);
    LOADPD(r3, 3 - wsk); LOADPD(r4, 4 - wsk); LOADPD(r5, 5 - wsk);
    LOADPD(r6, 6 - wsk); LOADPD(r7, 7 - wsk);

#define SCHAIN(CC, S_, SUX, SDX) do {                                          \
    float su_, sd_;                                                            \
    if (l == 0) {                                                              \
        if (w == 0) { su_ = BIGK; sd_ = ((S_) == 0) ? 0.0f : BIGK; }           \
        else        { su_ = (SUX); sd_ = (SDX); }                              \
    } else { su_ = nbc_s; sd_ = nbp_s; }                                       \
    if ((unsigned)j_ < 512u) {                                                 \
        float lAs = ps0;                                                       \
        float m1;                                                              \
        asm("v_min3_f32 %0, %1, %2, %3" : "=v"(m1) : "v"(su_), "v"(lAs), "v"(sd_)); \
        asm("v_exp_f32 %0, %1" : "=v"(eS) : "v"(m1 - su_));                    \
        asm("v_exp_f32 %0, %1" : "=v"(lS) : "v"(m1 - lAs));                    \
        asm("v_exp_f32 %0, %1" : "=v"(dS) : "v"(m1 - sd_));                    \
        float sA = (CC).x + m1;                                                \
        float m2;                                                              \
        asm("v_min3_f32 %0, %1, %2, %3" : "=v"(m2) : "v"(sA), "v"(ps1), "v"(lAs)); \
        asm("v_exp_f32 %0, %1" : "=v"(fS) : "v"(m2 - sA));                     \
        asm("v_exp_f32 %0, %1" : "=v"(gS) : "v"(m2 - ps1));                    \
        asm("v_exp_f32 %0, %1" : "=v"(hS) : "v"(m2 - lAs));                    \
        ps0 = sA;                                                              \
        ps1 = (CC).y + m2;                                                     \
    }                                                                          \
} while (0)

#define QRESOLVE(JR, QUY, QDY) do {                                            \
    float qu_, qd_;                                                            \
    if (l == 0) {                                                              \
        if (w == 0) { qu_ = 1.0f; qd_ = 1.0f; }                                \
        else        { qu_ = (QUY); qd_ = (QDY); }                              \
    } else { qu_ = nbc_q; qd_ = nbp_q; }                                       \
    if ((unsigned)(JR) < 512u) {                                               \
        float qAo = pq0;                                                       \
        float qA = __builtin_fmaf(qu_, eS, __builtin_fmaf(pq0, lS, qd_ * dS)); \
        float qB = __builtin_fmaf(qA, fS, __builtin_fmaf(pq1, gS, qAo * hS));  \
        pq0 = qA; pq1 = qB;                                                    \
    }                                                                          \
} while (0)

#define STEPN(REG, SIG, BSS, BSQ, SUX, SDX, QUY, QDY) do {                     \
    int s_ = sbase + (SIG);                                                    \
    int j_ = s_ - off;                                                         \
    f32x2 cc;                                                                  \
    asm volatile("s_waitcnt vmcnt(7)" : "=v"(cc) : "0"(REG));                  \
    QRESOLVE(j_ - 1, QUY, QDY);                                                \
    BSQ.y = pq1;                                                               \
    SCHAIN(cc, s_, SUX, SDX);                                                  \
    BSS.x = ps1;                                                               \
    float shs_, shq_;                                                          \
    asm("v_mov_b32_dpp %0, %2 wave_shr:1 row_mask:0xf bank_mask:0xf\n\t"       \
        "v_mov_b32_dpp %1, %3 wave_shr:1 row_mask:0xf bank_mask:0xf"           \
        : "=v"(shs_), "=v"(shq_) : "v"(ps1), "v"(pq1));                        \
    nbp_s = nbc_s; nbc_s = shs_;                                               \
    nbp_q = nbc_q; nbc_q = shq_;                                               \
    LOADPD(REG, s_ + RING - wsk);                                              \
} while (0)

#define STEP0(REG, BSS) do {                                                   \
    int s_ = sbase;                                                            \
    int j_ = s_ - off;                                                         \
    f32x2 cc;                                                                  \
    asm volatile("s_waitcnt vmcnt(7)" : "=v"(cc) : "0"(REG));                  \
    SCHAIN(cc, s_, c0[0], carry.x);                                            \
    BSS.x = ps1;                                                               \
    float shs_;                                                                \
    asm("v_mov_b32_dpp %0, %1 wave_shr:1 row_mask:0xf bank_mask:0xf"           \
        : "=v"(shs_) : "v"(ps1));                                              \
    nbp_s = nbc_s; nbc_s = shs_;                                               \
    nbp_q = nbc_q; nbc_q = qfl;                                                \
    LOADPD(REG, s_ + RING - wsk);                                              \
} while (0)

#define FLUSHQ() do {                                                          \
    int jr_ = sbase + 15 - off;                                                \
    QRESOLVE(jr_, c7[3], c7[1]);                                               \
    b15.y = pq1;                                                               \
    asm("v_mov_b32_dpp %0, %1 wave_shr:1 row_mask:0xf bank_mask:0xf"           \
        : "=v"(qfl) : "v"(pq1));                                               \
} while (0)

#define RENORMD(S, Q) do {                                                     \
    int e_ = (__float_as_int(Q) >> 23) - 127;                                  \
    Q = __int_as_float(__float_as_int(Q) - (e_ << 23));                        \
    S = S - (float)e_;                                                         \
} while (0)

    for (int I = 0; I < NITER; ++I) {
        asm volatile("s_waitcnt lgkmcnt(0)" ::: "memory");
        __builtin_amdgcn_s_barrier();
        asm volatile("" ::: "memory");
        const f32x4* rq = (const f32x4*)&buf[(I + 1) & 1][wm1][0];
        f32x4 c0 = rq[0], c1 = rq[1], c2 = rq[2], c3 = rq[3];
        f32x4 c4 = rq[4], c5 = rq[5], c6 = rq[6], c7 = rq[7];
        int sbase = I * KCH;
        STEP0(r0, b0);
        STEPN(r1, 1,  b1,  b0,  c0[2], c0[0], c0[1], carry.y);
        STEPN(r2, 2,  b2,  b1,  c1[0], c0[2], c0[3], c0[1]);
        STEPN(r3, 3,  b3,  b2,  c1[2], c1[0], c1[1], c0[3]);
        STEPN(r4, 4,  b4,  b3,  c2[0], c1[2], c1[3], c1[1]);
        STEPN(r5, 5,  b5,  b4,  c2[2], c2[0], c2[1], c1[3]);
        STEPN(r6, 6,  b6,  b5,  c3[0], c2[2], c2[3], c2[1]);
        STEPN(r7, 7,  b7,  b6,  c3[2], c3[0], c3[1], c2[3]);
        STEPN(r0, 8,  b8,  b7,  c4[0], c3[2], c3[3], c3[1]);
        STEPN(r1, 9,  b9,  b8,  c4[2], c4[0], c4[1], c3[3]);
        STEPN(r2, 10, b10, b9,  c5[0], c4[2], c4[3], c4[1]);
        STEPN(r3, 11, b11, b10, c5[2], c5[0], c5[1], c4[3]);
        STEPN(r4, 12, b12, b11, c6[0], c5[2], c5[3], c5[1]);
        STEPN(r5, 13, b13, b12, c6[2], c6[0], c6[1], c5[3]);
        STEPN(r6, 14, b14, b13, c7[0], c6[2], c6[3], c6[1]);
        STEPN(r7, 15, b15, b14, c7[2], c7[0], c7[1], c6[3]);
        FLUSHQ();
        carry = f32x2{c7[2], c7[3]};
        if (l == 63) {
            f32x2* wbp = &buf[I & 1][w][0];
            wbp[0]  = b0;  wbp[1]  = b1;  wbp[2]  = b2;  wbp[3]  = b3;
            wbp[4]  = b4;  wbp[5]  = b5;  wbp[6]  = b6;  wbp[7]  = b7;
            wbp[8]  = b8;  wbp[9]  = b9;  wbp[10] = b10; wbp[11] = b11;
            wbp[12] = b12; wbp[13] = b13; wbp[14] = b14; wbp[15] = b15;
        }
        RENORMD(ps0, pq0);
        RENORMD(ps1, pq1);
    }

    if (p == 255) {   // cell (511,511): q already resolved in-loop
        float lg;
        asm("v_log_f32 %0, %1" : "=v"(lg) : "v"(pq1));
        part[b] = (ps1 - lg) * LN2F;
    }
#undef STEPN
#undef STEP0
#undef FLUSHQ
#undef QRESOLVE
#undef SCHAIN
#undef LOADPD
#undef RENORMD
}

// ---------------------------------------------------------------------------
// Kernel 3: one-wave deterministic reduction. out = sum_b(R_b) / (B * N)
// ---------------------------------------------------------------------------
__global__ __launch_bounds__(64) void reduce_kernel(const float* __restrict__ part,
                                                    float* __restrict__ out) {
    int l = threadIdx.x;
    float v = part[l];
    #pragma unroll
    for (int m = 32; m >= 1; m >>= 1) v += __shfl_xor(v, m, 64);
    if (l == 0) out[0] = v / (float)(BATCH * NN);
}

// ---------------------------------------------------------------------------
extern "C" void kernel_launch(void* const* d_in, const int* in_sizes, int n_in,
                              void* d_out, int out_size, void* d_ws, size_t ws_size,
                              hipStream_t stream) {
    const float* X = (const float*)d_in[0];
    const float* Y = (const float*)d_in[1];
    float* out = (float*)d_out;
    char* ws = (char*)d_ws;

    const size_t cdBytes = (size_t)BATCH * NA * NP * 8;       // 96 MiB

    f32x2* Cd   = (f32x2*)ws;
    float* part = (float*)(ws + cdBytes);

    dim3 g(MM / 64, NN / 64, BATCH);
    cost_diag_mfma<<<g, 256, 0, stream>>>(X, Y, Cd);

    sdtw_diag_kernel<<<BATCH, 256, 0, stream>>>(Cd, part);

    reduce_kernel<<<1, 64, 0, stream>>>(part, out);
}